// Round 1
// baseline (1043.413 us; speedup 1.0000x reference)
//
#include <hip/hip_runtime.h>

#define EMBD 300
#define NSTEP 300
#define HID 512
#define G4 2048
#define NWG 32
#define TPB 256
#define TS 4                 // steps per phase-1 block

// ws layout (float indices):
//   [0]            : barrier counter (as unsigned)
//   [64 .. 64+1024): h double buffer [2][512]
//   [2048 .. )     : X_proj [300][2048]
#define HBUF_OFF 64
#define XP_OFF   2048

__device__ __forceinline__ float fsig(float x) { return 1.0f / (1.0f + __expf(-x)); }
__device__ __forceinline__ float ftanh(float x) {
    x = fminf(15.0f, fmaxf(-15.0f, x));
    float t = __expf(2.0f * x);
    return (t - 1.0f) / (t + 1.0f);
}

// Phase 1: X_proj[t][r] = b_ih[r] + b_hh[r] + sum_e W_ih[r][e] * emb[x[t]][e]
// Block bt handles t = bt*TS .. bt*TS+TS. Block 0 also initializes h-buffer + counter.
__global__ __launch_bounds__(TPB) void xproj_init_kernel(
    const int* __restrict__ x, const float* __restrict__ h0,
    const float* __restrict__ emb, const float* __restrict__ W_ih,
    const float* __restrict__ b_ih, const float* __restrict__ b_hh,
    float* __restrict__ ws) {
    const int bt = blockIdx.x;
    const int tid = threadIdx.x;

    if (bt == 0) {
        for (int i = tid; i < HID; i += TPB) ws[HBUF_OFF + i] = h0[i];
        if (tid == 0) ((unsigned*)ws)[0] = 0u;
    }

    __shared__ float e_lds[TS][EMBD];
    for (int tt = 0; tt < TS; ++tt) {
        const float* erow = emb + (long long)x[bt * TS + tt] * EMBD;
        for (int i = tid; i < EMBD; i += TPB) e_lds[tt][i] = erow[i];
    }
    __syncthreads();

    // 8 rows per thread: r = tid*8 + j
    float bs[8];
    #pragma unroll
    for (int j = 0; j < 8; ++j) {
        int r = tid * 8 + j;
        bs[j] = b_ih[r] + b_hh[r];
    }
    float acc[TS][8];
    #pragma unroll
    for (int tt = 0; tt < TS; ++tt)
        #pragma unroll
        for (int j = 0; j < 8; ++j) acc[tt][j] = bs[j];

    for (int e = 0; e < EMBD; e += 4) {
        #pragma unroll
        for (int j = 0; j < 8; ++j) {
            const float4 w4 = *(const float4*)(W_ih + (size_t)(tid * 8 + j) * EMBD + e);
            #pragma unroll
            for (int tt = 0; tt < TS; ++tt) {
                acc[tt][j] = fmaf(w4.x, e_lds[tt][e], acc[tt][j]);
                acc[tt][j] = fmaf(w4.y, e_lds[tt][e + 1], acc[tt][j]);
                acc[tt][j] = fmaf(w4.z, e_lds[tt][e + 2], acc[tt][j]);
                acc[tt][j] = fmaf(w4.w, e_lds[tt][e + 3], acc[tt][j]);
            }
        }
    }

    #pragma unroll
    for (int tt = 0; tt < TS; ++tt) {
        float* xp = ws + XP_OFF + (size_t)(bt * TS + tt) * G4;
        #pragma unroll
        for (int j = 0; j < 8; ++j) xp[tid * 8 + j] = acc[tt][j];
    }
}

// Phase 2: persistent cooperative scan. 32 WGs x 256 threads (all co-resident on
// 256 CUs). WG w owns h-indices [16w,16w+16): rows {g*512 + 16w + rr} for all 4
// gates g, so c-state and the pointwise update are WG-local; only h is exchanged
// per step via agent-scope atomics on a double buffer + one monotonic counter
// barrier per step (cross-XCD safe).
__global__ __launch_bounds__(TPB, 1) void lstm_scan_kernel(
    const float* __restrict__ c0, const float* __restrict__ W_hh,
    const float* __restrict__ fc_w, const float* __restrict__ fc_b,
    float* __restrict__ ws, float* __restrict__ out) {
    const int tid = threadIdx.x;
    const int wg = blockIdx.x;
    const int v = tid >> 6;      // wave id == gate id
    const int lane = tid & 63;
    const int g = lane >> 4;     // row-batch group within wave
    const int li = lane & 15;    // column-split lane within group
    const int j0 = wg * 16;

    unsigned* cnt = (unsigned*)ws;
    float* hbuf = ws + HBUF_OFF;           // [2][512]
    const float* xp = ws + XP_OFF;         // [300][2048]

    __shared__ __align__(16) float h_lds[576];  // idx i -> i + 4*(i>>5) (stride-36 chunks)
    __shared__ float g_lds[64];

    // W_hh slice in registers: wreg[b][k] = W_hh[v*512 + j0 + b*4 + g][li*32 + k]
    float wreg[4][32];
    #pragma unroll
    for (int b = 0; b < 4; ++b) {
        const float* wr = W_hh + (size_t)(v * HID + j0 + b * 4 + g) * HID + li * 32;
        #pragma unroll
        for (int k = 0; k < 32; k += 4) {
            const float4 w4 = *(const float4*)(wr + k);
            wreg[b][k] = w4.x; wreg[b][k + 1] = w4.y;
            wreg[b][k + 2] = w4.z; wreg[b][k + 3] = w4.w;
        }
    }

    float c = 0.0f;
    if (tid < 16) c = c0[j0 + tid];

    for (int s = 0; s < NSTEP; ++s) {
        if (s > 0) {
            if (tid == 0) {
                const unsigned target = (unsigned)(NWG * s);
                while (__hip_atomic_load(cnt, __ATOMIC_ACQUIRE, __HIP_MEMORY_SCOPE_AGENT) < target) {}
            }
            __syncthreads();
        }

        // Prefetch this step's X_proj for the update lanes (hidden under h load+dot).
        float xpi = 0.f, xpf = 0.f, xpg = 0.f, xpo = 0.f;
        if (tid < 16) {
            const float* xpt = xp + (size_t)s * G4 + j0 + tid;
            xpi = xpt[0]; xpf = xpt[HID]; xpg = xpt[2 * HID]; xpo = xpt[3 * HID];
        }

        // Stage h (agent-scope loads: bypass stale per-XCD caches) into padded LDS.
        {
            const float* hb = hbuf + (s & 1) * HID;
            const float hv0 = __hip_atomic_load(hb + tid, __ATOMIC_RELAXED, __HIP_MEMORY_SCOPE_AGENT);
            const float hv1 = __hip_atomic_load(hb + tid + 256, __ATOMIC_RELAXED, __HIP_MEMORY_SCOPE_AGENT);
            const int i0 = tid, i1 = tid + 256;
            h_lds[i0 + ((i0 >> 5) << 2)] = hv0;
            h_lds[i1 + ((i1 >> 5) << 2)] = hv1;
        }
        __syncthreads();

        // 4 rows per 16-lane group: 32 fmacs/row/lane + 4-stage butterfly reduce.
        float sums[4];
        const float* hrow = &h_lds[li * 36];
        #pragma unroll
        for (int b = 0; b < 4; ++b) {
            float acc = 0.0f;
            #pragma unroll
            for (int k = 0; k < 32; k += 4) {
                const float4 h4 = *(const float4*)(hrow + k);
                acc = fmaf(wreg[b][k], h4.x, acc);
                acc = fmaf(wreg[b][k + 1], h4.y, acc);
                acc = fmaf(wreg[b][k + 2], h4.z, acc);
                acc = fmaf(wreg[b][k + 3], h4.w, acc);
            }
            acc += __shfl_xor(acc, 1);
            acc += __shfl_xor(acc, 2);
            acc += __shfl_xor(acc, 4);
            acc += __shfl_xor(acc, 8);
            sums[b] = acc;
        }
        if (li == 0) {
            #pragma unroll
            for (int b = 0; b < 4; ++b) g_lds[v * 16 + b * 4 + g] = sums[b];
        }
        __syncthreads();

        // Pointwise LSTM update for this WG's 16 h-indices.
        if (tid < 16) {
            const float gi = g_lds[tid] + xpi;
            const float gf = g_lds[16 + tid] + xpf;
            const float gg = g_lds[32 + tid] + xpg;
            const float go = g_lds[48 + tid] + xpo;
            const float iv = fsig(gi);
            const float fv = fsig(gf);
            const float gv = ftanh(gg);
            const float ov = fsig(go);
            c = fv * c + iv * gv;
            const float h = ov * ftanh(c);
            __hip_atomic_store(hbuf + ((s + 1) & 1) * HID + j0 + tid, h,
                               __ATOMIC_RELAXED, __HIP_MEMORY_SCOPE_AGENT);
            if (s == NSTEP - 1) {
                out[1 + j0 + tid] = h;
                out[1 + HID + j0 + tid] = c;
            }
        }
        if (tid == 0) {
            __threadfence();  // wave-level vmcnt drain covers lanes 0..15 h-stores
            __hip_atomic_fetch_add(cnt, 1u, __ATOMIC_RELEASE, __HIP_MEMORY_SCOPE_AGENT);
        }
    }

    // Epilogue: WG 0 computes out[0] = sigmoid(fc_w . h_300 + fc_b).
    if (wg == 0) {
        if (tid == 0) {
            while (__hip_atomic_load(cnt, __ATOMIC_ACQUIRE, __HIP_MEMORY_SCOPE_AGENT)
                   < (unsigned)(NWG * NSTEP)) {}
        }
        __syncthreads();
        const float* hf = hbuf + (NSTEP & 1) * HID;  // h_300 lives in buffer 0
        float p = __hip_atomic_load(hf + tid, __ATOMIC_RELAXED, __HIP_MEMORY_SCOPE_AGENT) * fc_w[tid]
                + __hip_atomic_load(hf + tid + 256, __ATOMIC_RELAXED, __HIP_MEMORY_SCOPE_AGENT) * fc_w[tid + 256];
        h_lds[tid] = p;
        __syncthreads();
        for (int off = 128; off > 0; off >>= 1) {
            if (tid < off) h_lds[tid] += h_lds[tid + off];
            __syncthreads();
        }
        if (tid == 0) out[0] = fsig(h_lds[0] + fc_b[0]);
    }
}

extern "C" void kernel_launch(void* const* d_in, const int* in_sizes, int n_in,
                              void* d_out, int out_size, void* d_ws, size_t ws_size,
                              hipStream_t stream) {
    (void)in_sizes; (void)n_in; (void)out_size; (void)ws_size;
    const int*   x     = (const int*)d_in[0];
    const float* h0    = (const float*)d_in[1];
    const float* c0    = (const float*)d_in[2];
    const float* emb   = (const float*)d_in[3];
    const float* W_ih  = (const float*)d_in[4];
    const float* W_hh  = (const float*)d_in[5];
    const float* b_ih  = (const float*)d_in[6];
    const float* b_hh  = (const float*)d_in[7];
    const float* fc_w  = (const float*)d_in[8];
    const float* fc_b  = (const float*)d_in[9];
    float* out = (float*)d_out;
    float* ws  = (float*)d_ws;

    xproj_init_kernel<<<dim3(NSTEP / TS), dim3(TPB), 0, stream>>>(
        x, h0, emb, W_ih, b_ih, b_hh, ws);
    lstm_scan_kernel<<<dim3(NWG), dim3(TPB), 0, stream>>>(
        c0, W_hh, fc_w, fc_b, ws, out);
}

// Round 2
// 687.103 us; speedup vs baseline: 1.5186x; 1.5186x over previous
//
#include <hip/hip_runtime.h>

#define EMBD 300
#define NSTEP 300
#define HID 512
#define G4 2048
#define NWG 32
#define TPB 256

#define TS2 15      // steps per phase-1 step-group
#define NSG 20      // step groups (20*15 = 300)
#define NRG 8       // row groups (8*256 = 2048 rows)

#define SENTINEL 0xFFC00000u   // quiet NaN: h values are always finite

// ws float layout:
//   [0 .. 614400)            : X_proj [300][2048]
//   [614400 .. 614400+154112): HSEQ [301][512]  (h state before each step)
#define XP_SZ   (NSTEP * G4)
#define HSEQ_OFF XP_SZ

__device__ __forceinline__ float fsig(float x) { return 1.0f / (1.0f + __expf(-x)); }
__device__ __forceinline__ float ftanh(float x) {
    x = fminf(15.0f, fmaxf(-15.0f, x));
    float t = __expf(2.0f * x);
    return (t - 1.0f) / (t + 1.0f);
}

// Phase 1: X_proj[t][r] = b_ih[r]+b_hh[r] + sum_e W_ih[r][e]*emb[x[t]][e]
// Grid (NRG, NSG): block owns 256 rows (1/thread) x 15 steps.
// Also: sentinel-clears HSEQ rows 1..300 (every call -> replay safe) and
// copies h0 into HSEQ[0].
__global__ __launch_bounds__(TPB) void xproj_init_kernel(
    const int* __restrict__ x, const float* __restrict__ h0,
    const float* __restrict__ emb, const float* __restrict__ W_ih,
    const float* __restrict__ b_ih, const float* __restrict__ b_hh,
    float* __restrict__ ws) {
    const int rowg = blockIdx.x;      // 0..7
    const int sg   = blockIdx.y;      // 0..19
    const int tid  = threadIdx.x;
    const int t0   = sg * TS2;
    const int r    = rowg * TPB + tid;

    float* hseq = ws + HSEQ_OFF;

    if (rowg == 0) {
        unsigned* hs = (unsigned*)(hseq + (size_t)(t0 + 1) * HID);
        for (int i = tid; i < TS2 * HID; i += TPB) hs[i] = SENTINEL;
        if (sg == 0) {
            for (int i = tid; i < HID; i += TPB) hseq[i] = h0[i];
        }
    }

    __shared__ float e_lds[TS2][EMBD];
    for (int tt = 0; tt < TS2; ++tt) {
        const float* er = emb + (long long)x[t0 + tt] * EMBD;
        for (int i = tid; i < EMBD; i += TPB) e_lds[tt][i] = er[i];
    }
    __syncthreads();

    float acc[TS2];
    const float bsum = b_ih[r] + b_hh[r];
    #pragma unroll
    for (int tt = 0; tt < TS2; ++tt) acc[tt] = bsum;

    const float* wrow = W_ih + (size_t)r * EMBD;
    for (int e = 0; e < EMBD; e += 4) {          // 300 = 75 * 4, 16B-aligned rows
        const float4 w4 = *(const float4*)(wrow + e);
        #pragma unroll
        for (int tt = 0; tt < TS2; ++tt) {
            acc[tt] = fmaf(w4.x, e_lds[tt][e],     acc[tt]);
            acc[tt] = fmaf(w4.y, e_lds[tt][e + 1], acc[tt]);
            acc[tt] = fmaf(w4.z, e_lds[tt][e + 2], acc[tt]);
            acc[tt] = fmaf(w4.w, e_lds[tt][e + 3], acc[tt]);
        }
    }
    #pragma unroll
    for (int tt = 0; tt < TS2; ++tt)
        ws[(size_t)(t0 + tt) * G4 + r] = acc[tt];
}

// Phase 2: persistent 32-WG dataflow scan, no barriers, no counters.
// Each step s has its own h buffer HSEQ[s]; consumers spin on the data words
// themselves (sentinel = not written). 16-lane group (v,g) owns h-index
// hidx = 16*wg + 4*v + g: all 4 gate rows for it, so the pointwise update is
// done in-register by lane li==0 of the group (which also carries c).
__global__ __launch_bounds__(TPB, 1) void lstm_scan_kernel(
    const float* __restrict__ c0, const float* __restrict__ W_hh,
    const float* __restrict__ fc_w, const float* __restrict__ fc_b,
    float* __restrict__ ws, float* __restrict__ out) {
    const int tid  = threadIdx.x;
    const int wg   = blockIdx.x;
    const int v    = tid >> 6;     // wave id
    const int lane = tid & 63;
    const int g    = lane >> 4;    // group within wave
    const int li   = lane & 15;    // lane within group (column split)
    const int hidx = wg * 16 + v * 4 + g;

    float* hseq    = ws + HSEQ_OFF;        // [301][512]
    const float* xp = ws;                  // [300][2048]

    __shared__ __align__(16) float h_lds[576];   // idx i -> i + 4*(i>>5), stride-36 rows

    // W_hh slice in registers: wreg[gate][k] = W_hh[gate*512 + hidx][li*32 + k]
    float wreg[4][32];
    #pragma unroll
    for (int gate = 0; gate < 4; ++gate) {
        const float* wr = W_hh + ((size_t)gate * HID + hidx) * HID + li * 32;
        #pragma unroll
        for (int k = 0; k < 32; k += 4) {
            const float4 w4 = *(const float4*)(wr + k);
            wreg[gate][k] = w4.x; wreg[gate][k + 1] = w4.y;
            wreg[gate][k + 2] = w4.z; wreg[gate][k + 3] = w4.w;
        }
    }

    const bool upd = (li == 0);
    float c = upd ? c0[hidx] : 0.0f;

    for (int s = 0; s < NSTEP; ++s) {
        // X_proj loads issued before the poll -> latency hidden under it.
        float xi = 0.f, xf = 0.f, xg = 0.f, xo = 0.f;
        if (upd) {
            const float* xpt = xp + (size_t)s * G4 + hidx;
            xi = xpt[0]; xf = xpt[HID]; xg = xpt[2 * HID]; xo = xpt[3 * HID];
        }

        // Poll this step's h words (data-as-flag, agent scope).
        unsigned* hb = (unsigned*)(hseq + (size_t)s * HID);
        unsigned a = __hip_atomic_load(hb + tid,       __ATOMIC_RELAXED, __HIP_MEMORY_SCOPE_AGENT);
        unsigned b = __hip_atomic_load(hb + tid + 256, __ATOMIC_RELAXED, __HIP_MEMORY_SCOPE_AGENT);
        while (a == SENTINEL || b == SENTINEL) {
            __builtin_amdgcn_s_sleep(1);
            a = __hip_atomic_load(hb + tid,       __ATOMIC_RELAXED, __HIP_MEMORY_SCOPE_AGENT);
            b = __hip_atomic_load(hb + tid + 256, __ATOMIC_RELAXED, __HIP_MEMORY_SCOPE_AGENT);
        }
        const int i0 = tid, i1 = tid + 256;
        h_lds[i0 + ((i0 >> 5) << 2)] = __uint_as_float(a);
        h_lds[i1 + ((i1 >> 5) << 2)] = __uint_as_float(b);
        __syncthreads();

        // 4 gate rows for hidx: 32 cols/lane + 4-stage butterfly.
        float sums[4];
        const float* hrow = &h_lds[li * 36];
        #pragma unroll
        for (int gate = 0; gate < 4; ++gate) {
            float acc = 0.0f;
            #pragma unroll
            for (int k = 0; k < 32; k += 4) {
                const float4 h4 = *(const float4*)(hrow + k);
                acc = fmaf(wreg[gate][k],     h4.x, acc);
                acc = fmaf(wreg[gate][k + 1], h4.y, acc);
                acc = fmaf(wreg[gate][k + 2], h4.z, acc);
                acc = fmaf(wreg[gate][k + 3], h4.w, acc);
            }
            acc += __shfl_xor(acc, 1);
            acc += __shfl_xor(acc, 2);
            acc += __shfl_xor(acc, 4);
            acc += __shfl_xor(acc, 8);
            sums[gate] = acc;
        }

        if (upd) {
            const float iv = fsig(sums[0] + xi);
            const float fv = fsig(sums[1] + xf);
            const float gv = ftanh(sums[2] + xg);
            const float ov = fsig(sums[3] + xo);
            c = fv * c + iv * gv;
            const float h = ov * ftanh(c);
            __hip_atomic_store((unsigned*)(hseq + (size_t)(s + 1) * HID + hidx),
                               __float_as_uint(h),
                               __ATOMIC_RELAXED, __HIP_MEMORY_SCOPE_AGENT);
            if (s == NSTEP - 1) {
                out[1 + hidx] = h;
                out[1 + HID + hidx] = c;
            }
        }
        __syncthreads();   // protect h_lds reuse next iteration
    }

    // Epilogue: WG 0 computes out[0] = sigmoid(fc_w . h_300 + fc_b).
    if (wg == 0) {
        __syncthreads();
        unsigned* hf = (unsigned*)(hseq + (size_t)NSTEP * HID);
        unsigned a = __hip_atomic_load(hf + tid,       __ATOMIC_RELAXED, __HIP_MEMORY_SCOPE_AGENT);
        unsigned b = __hip_atomic_load(hf + tid + 256, __ATOMIC_RELAXED, __HIP_MEMORY_SCOPE_AGENT);
        while (a == SENTINEL || b == SENTINEL) {
            __builtin_amdgcn_s_sleep(1);
            a = __hip_atomic_load(hf + tid,       __ATOMIC_RELAXED, __HIP_MEMORY_SCOPE_AGENT);
            b = __hip_atomic_load(hf + tid + 256, __ATOMIC_RELAXED, __HIP_MEMORY_SCOPE_AGENT);
        }
        float p = __uint_as_float(a) * fc_w[tid] + __uint_as_float(b) * fc_w[tid + 256];
        h_lds[tid] = p;
        __syncthreads();
        for (int off = 128; off > 0; off >>= 1) {
            if (tid < off) h_lds[tid] += h_lds[tid + off];
            __syncthreads();
        }
        if (tid == 0) out[0] = fsig(h_lds[0] + fc_b[0]);
    }
}

extern "C" void kernel_launch(void* const* d_in, const int* in_sizes, int n_in,
                              void* d_out, int out_size, void* d_ws, size_t ws_size,
                              hipStream_t stream) {
    (void)in_sizes; (void)n_in; (void)out_size; (void)ws_size;
    const int*   x     = (const int*)d_in[0];
    const float* h0    = (const float*)d_in[1];
    const float* c0    = (const float*)d_in[2];
    const float* emb   = (const float*)d_in[3];
    const float* W_ih  = (const float*)d_in[4];
    const float* W_hh  = (const float*)d_in[5];
    const float* b_ih  = (const float*)d_in[6];
    const float* b_hh  = (const float*)d_in[7];
    const float* fc_w  = (const float*)d_in[8];
    const float* fc_b  = (const float*)d_in[9];
    float* out = (float*)d_out;
    float* ws  = (float*)d_ws;

    xproj_init_kernel<<<dim3(NRG, NSG), dim3(TPB), 0, stream>>>(
        x, h0, emb, W_ih, b_ih, b_hh, ws);
    lstm_scan_kernel<<<dim3(NWG), dim3(TPB), 0, stream>>>(
        c0, W_hh, fc_w, fc_b, ws, out);
}